// Round 2
// baseline (846.968 us; speedup 1.0000x reference)
//
#include <hip/hip_runtime.h>
#include <hip/hip_bf16.h>

#define B_ 4
#define S_ 2048
#define E_ 1024
#define H_ 16
#define D_ 64

typedef _Float16 f16;
typedef __attribute__((ext_vector_type(4))) float f32x4;
typedef __attribute__((ext_vector_type(8))) short bf16x8;
typedef __attribute__((ext_vector_type(8))) unsigned short u16x8;
typedef __attribute__((ext_vector_type(8))) _Float16 f16x8;
typedef __attribute__((ext_vector_type(4))) float float4v;

__device__ __forceinline__ unsigned short f2bf(float f) {
  union { float f; unsigned int u; } x; x.f = f;
  unsigned int u = x.u;
  u = (u + 0x7FFFu + ((u >> 16) & 1u)) >> 16;
  return (unsigned short)u;
}

#define MFMA_BF(a, b, c) __builtin_amdgcn_mfma_f32_16x16x32_bf16((a), (b), (c), 0, 0, 0)
#define MFMA_F16(a, b, c) __builtin_amdgcn_mfma_f32_16x16x32_f16((a), (b), (c), 0, 0, 0)

// fp32 [z][R][C] -> bf16 [z][C][R]
__global__ __launch_bounds__(256)
void transpose_convert(const float* __restrict__ src, unsigned short* __restrict__ dst,
                       int R, int C, float scale) {
  __shared__ unsigned short tile[64][65];
  const int rb = blockIdx.y * 64;
  const int cb = blockIdx.x * 64;
  const size_t mo = (size_t)blockIdx.z * (size_t)R * (size_t)C;
  const int t = threadIdx.x;
  const int r = t >> 2;
  const int c0 = (t & 3) * 16;
  const float* sp = src + mo + (size_t)(rb + r) * C + cb + c0;
#pragma unroll
  for (int j = 0; j < 16; j += 4) {
    float4v vv = *(const float4v*)(sp + j);
    tile[r][c0 + j + 0] = f2bf(vv[0] * scale);
    tile[r][c0 + j + 1] = f2bf(vv[1] * scale);
    tile[r][c0 + j + 2] = f2bf(vv[2] * scale);
    tile[r][c0 + j + 3] = f2bf(vv[3] * scale);
  }
  __syncthreads();
  u16x8 w0, w1;
#pragma unroll
  for (int j = 0; j < 8; ++j) w0[j] = tile[c0 + j][r];
#pragma unroll
  for (int j = 0; j < 8; ++j) w1[j] = tile[c0 + 8 + j][r];
  unsigned short* dp = dst + mo + (size_t)(cb + r) * R + rb + c0;
  *(u16x8*)(dp) = w0;
  *(u16x8*)(dp + 8) = w1;
}

// fp32 [z][R][C] -> f16 hi/lo [z][C][R] (2-way split, ~23-bit effective)
__global__ __launch_bounds__(256)
void transpose_split_f16(const float* __restrict__ src, f16* __restrict__ dhi,
                         f16* __restrict__ dlo, int R, int C, float scale) {
  __shared__ float tile[64][65];
  const int rb = blockIdx.y * 64;
  const int cb = blockIdx.x * 64;
  const size_t mo = (size_t)blockIdx.z * (size_t)R * (size_t)C;
  const int t = threadIdx.x;
  const int r = t >> 2;
  const int c0 = (t & 3) * 16;
  const float* sp = src + mo + (size_t)(rb + r) * C + cb + c0;
#pragma unroll
  for (int j = 0; j < 16; j += 4) {
    float4v vv = *(const float4v*)(sp + j);
    tile[r][c0 + j + 0] = vv[0] * scale;
    tile[r][c0 + j + 1] = vv[1] * scale;
    tile[r][c0 + j + 2] = vv[2] * scale;
    tile[r][c0 + j + 3] = vv[3] * scale;
  }
  __syncthreads();
  f16x8 h0, h1, l0, l1;
#pragma unroll
  for (int j = 0; j < 8; ++j) {
    float x = tile[c0 + j][r];
    f16 hi = (f16)x;
    h0[j] = hi; l0[j] = (f16)(x - (float)hi);
  }
#pragma unroll
  for (int j = 0; j < 8; ++j) {
    float x = tile[c0 + 8 + j][r];
    f16 hi = (f16)x;
    h1[j] = hi; l1[j] = (f16)(x - (float)hi);
  }
  const size_t o = mo + (size_t)(cb + r) * R + rb + c0;
  *(f16x8*)(dhi + o) = h0; *(f16x8*)(dhi + o + 8) = h1;
  *(f16x8*)(dlo + o) = l0; *(f16x8*)(dlo + o + 8) = l1;
}

// Q/K projection, split-f16 (3-term): out = X @ W[h], fp32-grade accuracy.
// X fp32 [b][s][e]; Whi/Wlo f16 [p][h][d][e]; out hi/lo f16 [p][b][h][s][d].
__global__ __launch_bounds__(256)
void proj_qk(const float* __restrict__ q, const float* __restrict__ k,
             const f16* __restrict__ Whi, const f16* __restrict__ Wlo,
             f16* __restrict__ out_hi, f16* __restrict__ out_lo) {
  __shared__ f16 Ah[128 * 32], Al[128 * 32];
  __shared__ f16 Bh[64 * 32], Bl[64 * 32];
  const int t = threadIdx.x;
  const int p = blockIdx.z >> 2;
  const int b = blockIdx.z & 3;
  const int h = blockIdx.y;
  const int s0 = blockIdx.x * 128;
  const float* X = p ? k : q;

  const int arow = t >> 1;
  const int ac0 = (t & 1) * 16;
  const float* aptr = X + ((size_t)b * S_ + s0 + arow) * E_ + ac0;

  const int brow = t >> 2;
  const int bc0 = (t & 3) * 8;
  const size_t wof = (((size_t)p * H_ + h) * D_ + brow) * E_ + bc0;

  const int w = t >> 6, l = t & 63, lr = l & 15, lg = l >> 4;

  f32x4 acc[2][4];
#pragma unroll
  for (int i = 0; i < 2; ++i)
#pragma unroll
    for (int c = 0; c < 4; ++c) acc[i][c] = (f32x4){0.f, 0.f, 0.f, 0.f};

  for (int e0 = 0; e0 < E_; e0 += 32) {
    __syncthreads();
    f16x8 h0, h1, l0, l1;
#pragma unroll
    for (int jj = 0; jj < 2; ++jj) {
      float4v va = *(const float4v*)(aptr + e0 + jj * 8);
      float4v vb = *(const float4v*)(aptr + e0 + jj * 8 + 4);
#pragma unroll
      for (int j = 0; j < 4; ++j) {
        f16 hi = (f16)va[j];
        (jj ? h1 : h0)[j] = hi;
        (jj ? l1 : l0)[j] = (f16)(va[j] - (float)hi);
      }
#pragma unroll
      for (int j = 0; j < 4; ++j) {
        f16 hi = (f16)vb[j];
        (jj ? h1 : h0)[4 + j] = hi;
        (jj ? l1 : l0)[4 + j] = (f16)(vb[j] - (float)hi);
      }
    }
    *(f16x8*)&Ah[arow * 32 + ac0] = h0; *(f16x8*)&Ah[arow * 32 + ac0 + 8] = h1;
    *(f16x8*)&Al[arow * 32 + ac0] = l0; *(f16x8*)&Al[arow * 32 + ac0 + 8] = l1;
    *(f16x8*)&Bh[brow * 32 + bc0] = *(const f16x8*)(Whi + wof + e0);
    *(f16x8*)&Bl[brow * 32 + bc0] = *(const f16x8*)(Wlo + wof + e0);
    __syncthreads();

    f16x8 ah0 = *(const f16x8*)&Ah[(w * 32 + lr) * 32 + lg * 8];
    f16x8 ah1 = *(const f16x8*)&Ah[(w * 32 + 16 + lr) * 32 + lg * 8];
    f16x8 al0 = *(const f16x8*)&Al[(w * 32 + lr) * 32 + lg * 8];
    f16x8 al1 = *(const f16x8*)&Al[(w * 32 + 16 + lr) * 32 + lg * 8];
#pragma unroll
    for (int c = 0; c < 4; ++c) {
      f16x8 bh = *(const f16x8*)&Bh[(c * 16 + lr) * 32 + lg * 8];
      f16x8 bl = *(const f16x8*)&Bl[(c * 16 + lr) * 32 + lg * 8];
      acc[0][c] = MFMA_F16(ah0, bh, acc[0][c]);
      acc[0][c] = MFMA_F16(ah0, bl, acc[0][c]);
      acc[0][c] = MFMA_F16(al0, bh, acc[0][c]);
      acc[1][c] = MFMA_F16(ah1, bh, acc[1][c]);
      acc[1][c] = MFMA_F16(ah1, bl, acc[1][c]);
      acc[1][c] = MFMA_F16(al1, bh, acc[1][c]);
    }
  }

  const size_t ob = (((size_t)p * B_ + b) * H_ + h) * (size_t)S_ * D_;
#pragma unroll
  for (int i = 0; i < 2; ++i)
#pragma unroll
    for (int c = 0; c < 4; ++c)
#pragma unroll
      for (int r = 0; r < 4; ++r) {
        const int row = w * 32 + i * 16 + lg * 4 + r;
        const int col = c * 16 + lr;
        float x = acc[i][c][r];
        f16 hi = (f16)x;
        out_hi[ob + (size_t)(s0 + row) * D_ + col] = hi;
        out_lo[ob + (size_t)(s0 + row) * D_ + col] = (f16)(x - (float)hi);
      }
}

// V projection, bf16 single: vh[b][h][s][d] = v @ Wv[h]
__global__ __launch_bounds__(256)
void proj_v(const float* __restrict__ v, const unsigned short* __restrict__ Wt,
            unsigned short* __restrict__ out) {
  __shared__ unsigned short As[128 * 32];
  __shared__ unsigned short Bs[64 * 32];
  const int t = threadIdx.x;
  const int b = blockIdx.z;
  const int h = blockIdx.y;
  const int s0 = blockIdx.x * 128;

  const int arow = t >> 1;
  const int ac0 = (t & 1) * 16;
  const float* aptr = v + ((size_t)b * S_ + s0 + arow) * E_ + ac0;

  const int brow = t >> 2;
  const int bc0 = (t & 3) * 8;
  const unsigned short* bptr = Wt + ((size_t)h * D_ + brow) * E_ + bc0;

  const int w = t >> 6, l = t & 63, lr = l & 15, lg = l >> 4;

  f32x4 acc[2][4];
#pragma unroll
  for (int i = 0; i < 2; ++i)
#pragma unroll
    for (int c = 0; c < 4; ++c) acc[i][c] = (f32x4){0.f, 0.f, 0.f, 0.f};

  for (int e0 = 0; e0 < E_; e0 += 32) {
    __syncthreads();
    float4v v0 = *(const float4v*)(aptr + e0);
    float4v v1 = *(const float4v*)(aptr + e0 + 4);
    float4v v2 = *(const float4v*)(aptr + e0 + 8);
    float4v v3 = *(const float4v*)(aptr + e0 + 12);
    u16x8 w0, w1;
#pragma unroll
    for (int j = 0; j < 4; ++j) { w0[j] = f2bf(v0[j]); w0[4 + j] = f2bf(v1[j]); }
#pragma unroll
    for (int j = 0; j < 4; ++j) { w1[j] = f2bf(v2[j]); w1[4 + j] = f2bf(v3[j]); }
    *(u16x8*)&As[arow * 32 + ac0] = w0;
    *(u16x8*)&As[arow * 32 + ac0 + 8] = w1;
    *(u16x8*)&Bs[brow * 32 + bc0] = *(const u16x8*)(bptr + e0);
    __syncthreads();

    bf16x8 af0 = *(const bf16x8*)&As[(w * 32 + lr) * 32 + lg * 8];
    bf16x8 af1 = *(const bf16x8*)&As[(w * 32 + 16 + lr) * 32 + lg * 8];
#pragma unroll
    for (int c = 0; c < 4; ++c) {
      bf16x8 bf = *(const bf16x8*)&Bs[(c * 16 + lr) * 32 + lg * 8];
      acc[0][c] = MFMA_BF(af0, bf, acc[0][c]);
      acc[1][c] = MFMA_BF(af1, bf, acc[1][c]);
    }
  }

  unsigned short* op = out + ((size_t)b * H_ + h) * (size_t)S_ * D_;
#pragma unroll
  for (int i = 0; i < 2; ++i)
#pragma unroll
    for (int c = 0; c < 4; ++c)
#pragma unroll
      for (int r = 0; r < 4; ++r) {
        const int row = w * 32 + i * 16 + lg * 4 + r;
        const int col = c * 16 + lr;
        op[(size_t)(s0 + row) * D_ + col] = f2bf(acc[i][c][r]);
      }
}

// Causal flash attention; QK^T in split-f16 (3-term), PV in bf16.
__global__ __launch_bounds__(256)
void attn_kernel(const f16* __restrict__ qhh, const f16* __restrict__ qhl,
                 const f16* __restrict__ khh, const f16* __restrict__ khl,
                 const unsigned short* __restrict__ vh, unsigned short* __restrict__ ao) {
  __shared__ f16 Ksh[32 * 64];
  __shared__ f16 Ksl[32 * 64];
  __shared__ unsigned short Vt[64 * 32];
  __shared__ unsigned short Pl[4 * 16 * 32];
  const int t = threadIdx.x;
  const int b = blockIdx.z, h = blockIdx.y;
  const int q0 = blockIdx.x * 64;
  const int w = t >> 6, l = t & 63, lr = l & 15, lg = l >> 4;
  const size_t bh = ((size_t)b * H_ + h) * S_;

  f16x8 qh0, qh1, ql0, ql1;
  {
    const size_t qo = (bh + q0 + w * 16 + lr) * D_ + lg * 8;
    qh0 = *(const f16x8*)(qhh + qo);
    qh1 = *(const f16x8*)(qhh + qo + 32);
    ql0 = *(const f16x8*)(qhl + qo);
    ql1 = *(const f16x8*)(qhl + qo + 32);
  }
  f32x4 acc[4];
#pragma unroll
  for (int c = 0; c < 4; ++c) acc[c] = (f32x4){0.f, 0.f, 0.f, 0.f};
  float m[4] = {-3.0e38f, -3.0e38f, -3.0e38f, -3.0e38f};
  float ls[4] = {0.f, 0.f, 0.f, 0.f};

  const int srow = t >> 3;
  const int sc0 = (t & 7) * 8;
  const size_t kvo = (bh + srow) * D_ + sc0;

  const int nkt = q0 / 32 + 2;
  for (int kt = 0; kt < nkt; ++kt) {
    const int kt0 = kt * 32;
    __syncthreads();
    *(f16x8*)&Ksh[srow * 64 + sc0] = *(const f16x8*)(khh + kvo + (size_t)kt0 * D_);
    *(f16x8*)&Ksl[srow * 64 + sc0] = *(const f16x8*)(khl + kvo + (size_t)kt0 * D_);
    u16x8 vv = *(const u16x8*)(vh + kvo + (size_t)kt0 * D_);
#pragma unroll
    for (int j = 0; j < 8; ++j) Vt[(sc0 + j) * 32 + srow] = vv[j];
    __syncthreads();

    f32x4 sc[2];
#pragma unroll
    for (int n = 0; n < 2; ++n) {
      f16x8 kh0 = *(const f16x8*)&Ksh[(n * 16 + lr) * 64 + lg * 8];
      f16x8 kh1 = *(const f16x8*)&Ksh[(n * 16 + lr) * 64 + 32 + lg * 8];
      f16x8 kl0 = *(const f16x8*)&Ksl[(n * 16 + lr) * 64 + lg * 8];
      f16x8 kl1 = *(const f16x8*)&Ksl[(n * 16 + lr) * 64 + 32 + lg * 8];
      f32x4 z = (f32x4){0.f, 0.f, 0.f, 0.f};
      z = MFMA_F16(qh0, kh0, z);
      z = MFMA_F16(qh1, kh1, z);
      z = MFMA_F16(qh0, kl0, z);
      z = MFMA_F16(qh1, kl1, z);
      z = MFMA_F16(ql0, kh0, z);
      z = MFMA_F16(ql1, kh1, z);
      sc[n] = z;
    }

#pragma unroll
    for (int r = 0; r < 4; ++r) {
      const int qrow = q0 + w * 16 + lg * 4 + r;
      float s0v = (kt0 + lr <= qrow) ? sc[0][r] : -3.0e38f;
      float s1v = (kt0 + 16 + lr <= qrow) ? sc[1][r] : -3.0e38f;
      float tm = fmaxf(s0v, s1v);
      tm = fmaxf(tm, __shfl_xor(tm, 1));
      tm = fmaxf(tm, __shfl_xor(tm, 2));
      tm = fmaxf(tm, __shfl_xor(tm, 4));
      tm = fmaxf(tm, __shfl_xor(tm, 8));
      const float mn = fmaxf(m[r], tm);
      const float corr = __expf(m[r] - mn);
      const float p0 = __expf(s0v - mn);
      const float p1 = __expf(s1v - mn);
      float ps = p0 + p1;
      ps += __shfl_xor(ps, 1);
      ps += __shfl_xor(ps, 2);
      ps += __shfl_xor(ps, 4);
      ps += __shfl_xor(ps, 8);
      ls[r] = ls[r] * corr + ps;
      m[r] = mn;
#pragma unroll
      for (int c = 0; c < 4; ++c) acc[c][r] *= corr;
      Pl[(w * 16 + lg * 4 + r) * 32 + lr] = f2bf(p0);
      Pl[(w * 16 + lg * 4 + r) * 32 + 16 + lr] = f2bf(p1);
    }
    __syncthreads();

    bf16x8 pf = *(const bf16x8*)&Pl[(w * 16 + lr) * 32 + lg * 8];
#pragma unroll
    for (int c = 0; c < 4; ++c) {
      bf16x8 vf = *(const bf16x8*)&Vt[(c * 16 + lr) * 32 + lg * 8];
      acc[c] = MFMA_BF(pf, vf, acc[c]);
    }
  }

#pragma unroll
  for (int r = 0; r < 4; ++r) {
    const float inv = 1.0f / ls[r];
    const size_t o = ((size_t)(b * S_ + q0 + w * 16 + lg * 4 + r) * H_ + h) * D_;
#pragma unroll
    for (int c = 0; c < 4; ++c)
      ao[o + c * 16 + lr] = f2bf(acc[c][r] * inv);
  }
}

// Output projection: d_out[m][n] = sum_k ao[m][k] * Wo[k][n] (Wot = Wo^T bf16)
__global__ __launch_bounds__(256)
void out_gemm(const unsigned short* __restrict__ A, const unsigned short* __restrict__ Bt,
              float* __restrict__ Cout) {
  __shared__ unsigned short As[128 * 32];
  __shared__ unsigned short Bs[64 * 32];
  const int t = threadIdx.x;
  const int m0 = blockIdx.x * 128;
  const int n0 = blockIdx.y * 64;
  const int arow = t >> 1, ac0 = (t & 1) * 16;
  const unsigned short* aptr = A + (size_t)(m0 + arow) * 1024 + ac0;
  const int brow = t >> 2, bc0 = (t & 3) * 8;
  const unsigned short* bptr = Bt + (size_t)(n0 + brow) * 1024 + bc0;
  const int w = t >> 6, l = t & 63, lr = l & 15, lg = l >> 4;

  f32x4 acc[2][4];
#pragma unroll
  for (int i = 0; i < 2; ++i)
#pragma unroll
    for (int c = 0; c < 4; ++c) acc[i][c] = (f32x4){0.f, 0.f, 0.f, 0.f};

  for (int k0 = 0; k0 < 1024; k0 += 32) {
    __syncthreads();
    *(u16x8*)&As[arow * 32 + ac0] = *(const u16x8*)(aptr + k0);
    *(u16x8*)&As[arow * 32 + ac0 + 8] = *(const u16x8*)(aptr + k0 + 8);
    *(u16x8*)&Bs[brow * 32 + bc0] = *(const u16x8*)(bptr + k0);
    __syncthreads();

    bf16x8 af0 = *(const bf16x8*)&As[(w * 32 + lr) * 32 + lg * 8];
    bf16x8 af1 = *(const bf16x8*)&As[(w * 32 + 16 + lr) * 32 + lg * 8];
#pragma unroll
    for (int c = 0; c < 4; ++c) {
      bf16x8 bf = *(const bf16x8*)&Bs[(c * 16 + lr) * 32 + lg * 8];
      acc[0][c] = MFMA_BF(af0, bf, acc[0][c]);
      acc[1][c] = MFMA_BF(af1, bf, acc[1][c]);
    }
  }

#pragma unroll
  for (int i = 0; i < 2; ++i)
#pragma unroll
    for (int c = 0; c < 4; ++c)
#pragma unroll
      for (int r = 0; r < 4; ++r) {
        const int row = m0 + w * 32 + i * 16 + lg * 4 + r;
        const int col = n0 + c * 16 + lr;
        Cout[(size_t)row * 1024 + col] = acc[i][c][r];
      }
}

extern "C" void kernel_launch(void* const* d_in, const int* in_sizes, int n_in,
                              void* d_out, int out_size, void* d_ws, size_t ws_size,
                              hipStream_t stream) {
  const float* q = (const float*)d_in[0];
  const float* k = (const float*)d_in[1];
  const float* v = (const float*)d_in[2];
  const float* Wq = (const float*)d_in[3];
  const float* Wk = (const float*)d_in[4];
  const float* Wv = (const float*)d_in[5];
  const float* Wo = (const float*)d_in[6];

  const size_t NBH = (size_t)B_ * H_ * S_ * D_;   // 8388608
  const size_t WSZ = (size_t)H_ * D_ * E_;        // 1048576

  char* wsb = (char*)d_ws;
  f16* qk_hi = (f16*)wsb;                          // [2][B][H][S][D]
  f16* qk_lo = qk_hi + 2 * NBH;                    // [2][B][H][S][D]
  unsigned short* vh = (unsigned short*)(qk_lo + 2 * NBH);   // [B][H][S][D]
  unsigned short* ao = vh + NBH;                   // [B][S][H][D]
  f16* Wqk_hi = (f16*)(ao + NBH);                  // [2][H][D][E]
  f16* Wqk_lo = Wqk_hi + 2 * WSZ;
  unsigned short* Wvt = (unsigned short*)(Wqk_lo + 2 * WSZ); // [H][D][E]
  unsigned short* Wot = Wvt + WSZ;                 // [E][H*D]

  dim3 blk(256);
  // Weight prep (x8 quirk folded into Wq, exact).
  transpose_split_f16<<<dim3(1, 16, 16), blk, 0, stream>>>(Wq, Wqk_hi, Wqk_lo, E_, D_, 8.0f);
  transpose_split_f16<<<dim3(1, 16, 16), blk, 0, stream>>>(Wk, Wqk_hi + WSZ, Wqk_lo + WSZ, E_, D_, 1.0f);
  transpose_convert<<<dim3(1, 16, 16), blk, 0, stream>>>(Wv, Wvt, E_, D_, 1.0f);
  transpose_convert<<<dim3(16, 16, 1), blk, 0, stream>>>(Wo, Wot, E_, E_, 1.0f);
  // Projections.
  proj_qk<<<dim3(S_ / 128, H_, 8), blk, 0, stream>>>(q, k, Wqk_hi, Wqk_lo, qk_hi, qk_lo);
  proj_v<<<dim3(S_ / 128, H_, B_), blk, 0, stream>>>(v, Wvt, vh);
  // Attention.
  attn_kernel<<<dim3(S_ / 64, H_, B_), blk, 0, stream>>>(
      qk_hi, qk_lo, qk_hi + NBH, qk_lo + NBH, vh, ao);
  // Output projection.
  out_gemm<<<dim3((B_ * S_) / 128, E_ / 64), blk, 0, stream>>>(ao, Wot, (float*)d_out);
}